// Round 6
// baseline (395.118 us; speedup 1.0000x reference)
//
#include <hip/hip_runtime.h>
#include <math.h>

// Problem constants
#define BB 2
#define LL 1024
#define HH 1024
#define NH 16
#define DD 64
#define HD (NH * DD)   // 1024
#define MM (BB * LL)   // 2048
#define RCT 32         // recurrence chunk length staged in LDS
#define KEXT 3072      // extended K for f16 hi/lo split GEMM (3 x 1024)
#define NB_QKV 3200    // Be rows: 3072 qkv + 32 alpha/beta + 96 zero pad

typedef _Float16 f16x8 __attribute__((ext_vector_type(8)));
typedef _Float16 f16x4 __attribute__((ext_vector_type(4)));
typedef float f32x4 __attribute__((ext_vector_type(4)));

// ---------------------------------------------------------------------------
// async global->LDS, 16B per lane; LDS dest = wave-uniform base + lane*16
// ---------------------------------------------------------------------------
__device__ __forceinline__ void load_lds16(const void* g, void* l) {
    __builtin_amdgcn_global_load_lds(
        (const __attribute__((address_space(1))) void*)g,
        (__attribute__((address_space(3))) void*)l, 16, 0, 0);
}

// ---------------------------------------------------------------------------
// Split-f16 conversion kernels (unchanged from round 5).
// ---------------------------------------------------------------------------
__global__ __launch_bounds__(256) void convert_A(
    const float* __restrict__ X, _Float16* __restrict__ Ae, float scale)
{
    const int row = blockIdx.x;
    const int t = threadIdx.x;
    float4 x = *(const float4*)(X + (size_t)row * 1024 + t * 4);
    x.x *= scale; x.y *= scale; x.z *= scale; x.w *= scale;
    f16x4 h, l;
    h[0] = (_Float16)x.x; l[0] = (_Float16)(x.x - (float)h[0]);
    h[1] = (_Float16)x.y; l[1] = (_Float16)(x.y - (float)h[1]);
    h[2] = (_Float16)x.z; l[2] = (_Float16)(x.z - (float)h[2]);
    h[3] = (_Float16)x.w; l[3] = (_Float16)(x.w - (float)h[3]);
    _Float16* base = Ae + (size_t)row * KEXT + t * 4;
    *(f16x4*)(base)        = h;
    *(f16x4*)(base + 1024) = l;
    *(f16x4*)(base + 2048) = h;
}

__global__ __launch_bounds__(256) void convert_Wqkv(
    const float* __restrict__ Wq, const float* __restrict__ Wk,
    const float* __restrict__ Wv, const float* __restrict__ Wa,
    const float* __restrict__ Wb, _Float16* __restrict__ Be)
{
    const int n = blockIdx.x;
    const int t = threadIdx.x;
    const float* src = nullptr;
    if (n < 1024)      src = Wq + (size_t)n * 1024;
    else if (n < 2048) src = Wk + (size_t)(n - 1024) * 1024;
    else if (n < 3072) src = Wv + (size_t)(n - 2048) * 1024;
    else if (n < 3088) src = Wa + (size_t)(n - 3072) * 1024;
    else if (n < 3104) src = Wb + (size_t)(n - 3088) * 1024;
    float4 x = src ? *(const float4*)(src + t * 4) : make_float4(0.f,0.f,0.f,0.f);
    x.x *= 64.f; x.y *= 64.f; x.z *= 64.f; x.w *= 64.f;
    f16x4 h, l;
    h[0] = (_Float16)x.x; l[0] = (_Float16)(x.x - (float)h[0]);
    h[1] = (_Float16)x.y; l[1] = (_Float16)(x.y - (float)h[1]);
    h[2] = (_Float16)x.z; l[2] = (_Float16)(x.z - (float)h[2]);
    h[3] = (_Float16)x.w; l[3] = (_Float16)(x.w - (float)h[3]);
    _Float16* base = Be + (size_t)n * KEXT + t * 4;
    *(f16x4*)(base)        = h;
    *(f16x4*)(base + 1024) = h;
    *(f16x4*)(base + 2048) = l;
}

__global__ __launch_bounds__(256) void convert_Wo(
    const float* __restrict__ Wo, _Float16* __restrict__ Be)
{
    const int n = blockIdx.x;
    const int t = threadIdx.x;
    float4 x = *(const float4*)(Wo + (size_t)n * 1024 + t * 4);
    x.x *= 64.f; x.y *= 64.f; x.z *= 64.f; x.w *= 64.f;
    f16x4 h, l;
    h[0] = (_Float16)x.x; l[0] = (_Float16)(x.x - (float)h[0]);
    h[1] = (_Float16)x.y; l[1] = (_Float16)(x.y - (float)h[1]);
    h[2] = (_Float16)x.z; l[2] = (_Float16)(x.z - (float)h[2]);
    h[3] = (_Float16)x.w; l[3] = (_Float16)(x.w - (float)h[3]);
    _Float16* base = Be + (size_t)n * KEXT + t * 4;
    *(f16x4*)(base)        = h;
    *(f16x4*)(base + 1024) = h;
    *(f16x4*)(base + 2048) = l;
}

// ---------------------------------------------------------------------------
// MFMA GEMM (unchanged from round 5).
// ---------------------------------------------------------------------------
__global__ __launch_bounds__(256) void mfma_gemm(
    const _Float16* __restrict__ Ae, const _Float16* __restrict__ Be,
    float* __restrict__ qkv, float* __restrict__ ab,
    const float* __restrict__ bq, const float* __restrict__ bk,
    const float* __restrict__ bv,
    float* __restrict__ outp, const float* __restrict__ bo, int mode)
{
    __shared__ __align__(16) _Float16 As[128 * 32];
    __shared__ __align__(16) _Float16 Bs[128 * 32];

    const int tid = threadIdx.x;
    const int wave = tid >> 6;
    const int lane = tid & 63;
    const int bm = blockIdx.y * 128;
    const int bn = blockIdx.x * 128;
    const int wr = (wave >> 1) * 64;
    const int wc = (wave & 1) * 64;

    const int srow = lane >> 2;
    const int scol = (lane & 3) * 8;
    const _Float16* gA0 = Ae + (size_t)(bm + wave * 32 + srow) * KEXT + scol;
    const _Float16* gA1 = gA0 + (size_t)16 * KEXT;
    const _Float16* gB0 = Be + (size_t)(bn + wave * 32 + srow) * KEXT + scol;
    const _Float16* gB1 = gB0 + (size_t)16 * KEXT;
    _Float16* lA0 = &As[(wave * 32) * 32];
    _Float16* lA1 = &As[(wave * 32 + 16) * 32];
    _Float16* lB0 = &Bs[(wave * 32) * 32];
    _Float16* lB1 = &Bs[(wave * 32 + 16) * 32];

    const int fm = lane & 15;
    const int fq = (lane >> 4) * 8;

    f32x4 acc[4][4] = {};

    for (int k0 = 0; k0 < KEXT; k0 += 32) {
        load_lds16(gA0 + k0, lA0);
        load_lds16(gA1 + k0, lA1);
        load_lds16(gB0 + k0, lB0);
        load_lds16(gB1 + k0, lB1);
        __syncthreads();

        f16x8 a[4], b[4];
        #pragma unroll
        for (int mt = 0; mt < 4; ++mt)
            a[mt] = *(const f16x8*)&As[(wr + mt * 16 + fm) * 32 + fq];
        #pragma unroll
        for (int nt = 0; nt < 4; ++nt)
            b[nt] = *(const f16x8*)&Bs[(wc + nt * 16 + fm) * 32 + fq];
        #pragma unroll
        for (int mt = 0; mt < 4; ++mt)
            #pragma unroll
            for (int nt = 0; nt < 4; ++nt)
                acc[mt][nt] = __builtin_amdgcn_mfma_f32_16x16x32_f16(
                    a[mt], b[nt], acc[mt][nt], 0, 0, 0);
        __syncthreads();
    }

    const int rquad = (lane >> 4) * 4;
    #pragma unroll
    for (int mt = 0; mt < 4; ++mt) {
        #pragma unroll
        for (int nt = 0; nt < 4; ++nt) {
            const int col = bn + wc + nt * 16 + fm;
            #pragma unroll
            for (int i = 0; i < 4; ++i) {
                const int row = bm + wr + mt * 16 + rquad + i;
                float val = acc[mt][nt][i];
                if (mode == 0) {
                    val *= (1.0f / 1024.0f);
                    if (col < 1024)
                        qkv[(size_t)row * 3072 + col] = val + bq[col];
                    else if (col < 2048)
                        qkv[(size_t)row * 3072 + col] = val + bk[col - 1024];
                    else if (col < 3072)
                        qkv[(size_t)row * 3072 + col] = val + bv[col - 2048];
                    else {
                        const int c = col - 3072;
                        if (c < 16)
                            ab[(size_t)row * 32 + c] = 1.f / (1.f + expf(-val));
                        else if (c < 32)
                            ab[(size_t)row * 32 + c] =
                                fmaxf(val, 0.f) + log1pf(expf(-fabsf(val)));
                    }
                } else {
                    outp[(size_t)row * 1024 + col] = val * 64.f + bo[col];
                }
            }
        }
    }
}

// ---------------------------------------------------------------------------
// Gram/scalar pre-kernel: scal[(b*L+t)*16+h] = {alpha, beta, k_t.k_{t+1}, k_t.q_t}
// These are S-independent, shared by all 16 row-slices of a chain — computing
// them once here removes 2 dots + 2 red16 from every gdn step.
// ---------------------------------------------------------------------------
__global__ __launch_bounds__(256) void gdn_dots(
    const float* __restrict__ qkv, const float* __restrict__ ab,
    float4* __restrict__ scal)
{
    const int bh = blockIdx.y;            // 0..31
    const int t  = blockIdx.x * 256 + threadIdx.x;  // 0..1023
    const int b = bh >> 4;
    const int h = bh & 15;
    const size_t row = (size_t)b * LL + t;
    const float* kp = qkv + row * 3072 + 1024 + h * 64;
    const float* qp = qkv + row * 3072 + h * 64;
    const float* kp2 = (t < LL - 1) ? kp + 3072 : kp;

    float kk0 = 0.f, kk1 = 0.f, qk0 = 0.f, qk1 = 0.f;
    #pragma unroll
    for (int i = 0; i < 16; i += 2) {
        float4 a = *(const float4*)(kp + i * 4);
        float4 c = *(const float4*)(kp2 + i * 4);
        float4 d = *(const float4*)(qp + i * 4);
        kk0 = fmaf(a.x, c.x, kk0); kk0 = fmaf(a.y, c.y, kk0);
        kk0 = fmaf(a.z, c.z, kk0); kk0 = fmaf(a.w, c.w, kk0);
        qk0 = fmaf(a.x, d.x, qk0); qk0 = fmaf(a.y, d.y, qk0);
        qk0 = fmaf(a.z, d.z, qk0); qk0 = fmaf(a.w, d.w, qk0);
        float4 a2 = *(const float4*)(kp + i * 4 + 4);
        float4 c2 = *(const float4*)(kp2 + i * 4 + 4);
        float4 d2 = *(const float4*)(qp + i * 4 + 4);
        kk1 = fmaf(a2.x, c2.x, kk1); kk1 = fmaf(a2.y, c2.y, kk1);
        kk1 = fmaf(a2.z, c2.z, kk1); kk1 = fmaf(a2.w, c2.w, kk1);
        qk1 = fmaf(a2.x, d2.x, qk1); qk1 = fmaf(a2.y, d2.y, qk1);
        qk1 = fmaf(a2.z, d2.z, qk1); qk1 = fmaf(a2.w, d2.w, qk1);
    }
    float al = ab[row * 32 + h];
    float be = ab[row * 32 + 16 + h];
    scal[row * 16 + h] = make_float4(al, be, kk0 + kk1, qk0 + qk1);
}

// ---------------------------------------------------------------------------
// DPP 16-lane reduction
// ---------------------------------------------------------------------------
template <int CTRL>
__device__ __forceinline__ float dpp_addf(float x) {
    int y = __builtin_amdgcn_update_dpp(0, __builtin_bit_cast(int, x),
                                        CTRL, 0xF, 0xF, true);
    return x + __builtin_bit_cast(float, y);
}
__device__ __forceinline__ float red16(float x) {
    x = dpp_addf<0xB1>(x);
    x = dpp_addf<0x4E>(x);
    x = dpp_addf<0x124>(x);
    x = dpp_addf<0x128>(x);
    return x;
}

// ---------------------------------------------------------------------------
// Gated delta recurrence with one-step algebraic lookahead.
//   sk_{t+1} = a_t*(S_{t-1}.k_{t+1}) + cf_t*(k_t.k_{t+1})
//   o_t      = a_t*(S_{t-1}.q_t)     + cf_t*(k_t.q_t)
// Serial chain per step = 2 scalar FMAs; red16s run one iteration early.
// Triple-buffered LDS chunks (step t touches data up to t+3); circular
// register queues with full unroll-4 renaming; flight distance 3 on LDS reads.
// 512 blocks x 64 threads; blk%32 = chain (XCD co-location), blk/32 = slice.
// ---------------------------------------------------------------------------
__global__ __launch_bounds__(64) void gdn_recurrence(
    const float* __restrict__ qkv, const float4* __restrict__ scal,
    float* __restrict__ att)
{
    __shared__ __align__(16) float ks[3][RCT][64];
    __shared__ __align__(16) float qs[3][RCT][64];
    __shared__ __align__(16) float vs_[3][RCT][4];
    __shared__ __align__(16) float4 ss[3][RCT];

    const int blk = blockIdx.x;
    const int bh = blk & 31;
    const int s  = blk >> 5;
    const int b  = bh >> 4;
    const int h  = bh & 15;
    const int lane = threadIdx.x;
    const int rl = lane >> 4;
    const int el = lane & 15;
    const int e0 = el * 4;
    const int r0 = s * 4;

    const float* qb  = qkv + (size_t)b * LL * 3072 + h * 64;
    const float* kb  = qb + 1024;
    const float* vb  = qb + 2048 + r0;
    const float4* sp = scal + (size_t)b * LL * 16 + h;
    float* op = att + ((size_t)(b * NH + h) * DD + r0 + rl) * LL;

    // staging lane mapping for k/q: lane covers (t-within-4, d)
    const int st = lane >> 4;
    const int sd = (lane & 15) * 4;

    float S0 = 0.f, S1 = 0.f, S2 = 0.f, S3 = 0.f;
    float skc = 0.f;

    // ---- stage chunks 0 and 1 ----
    #pragma unroll
    for (int c0 = 0; c0 < 2; ++c0) {
        const size_t t0 = (size_t)c0 * RCT;
        const size_t ro = (t0 + st) * 3072 + sd;
        #pragma unroll
        for (int m = 0; m < 8; ++m) {
            load_lds16(kb + ro + (size_t)m * 4 * 3072, &ks[c0][m * 4][0]);
            load_lds16(qb + ro + (size_t)m * 4 * 3072, &qs[c0][m * 4][0]);
        }
        if (lane < RCT) {
            load_lds16(vb + (t0 + lane) * 3072, &vs_[c0][0][0]);
            load_lds16(sp + (t0 + lane) * 16, &ss[c0][0]);
        }
    }
    __syncthreads();

    // ---- preload register queues: slots 0,1,2 ----
    float4 kr[4], qr[4], sr[4];
    float vr[4];
    #pragma unroll
    for (int i = 0; i < 3; ++i) {
        kr[i] = *(const float4*)&ks[0][i][e0];
        qr[i] = *(const float4*)&qs[0][i][e0];
        sr[i] = ss[0][i];
        vr[i] = vs_[0][i][rl];
    }

    float o0 = 0.f, o1 = 0.f, o2 = 0.f;

    const int NCHUNK = LL / RCT;
    for (int c = 0; c < NCHUNK; ++c) {
        // issue async staging for chunk c+2 into buffer (c+2)%3
        if (c + 2 < NCHUNK) {
            const int nb = (c + 2) % 3;
            const size_t t0 = (size_t)(c + 2) * RCT;
            const size_t ro = (t0 + st) * 3072 + sd;
            #pragma unroll
            for (int m = 0; m < 8; ++m) {
                load_lds16(kb + ro + (size_t)m * 4 * 3072, &ks[nb][m * 4][0]);
                load_lds16(qb + ro + (size_t)m * 4 * 3072, &qs[nb][m * 4][0]);
            }
            if (lane < RCT) {
                load_lds16(vb + (t0 + lane) * 3072, &vs_[nb][0][0]);
                load_lds16(sp + (t0 + lane) * 16, &ss[nb][0]);
            }
        }

        #pragma unroll 4
        for (int t = 0; t < RCT; ++t) {
            const int g = c * RCT + t;
            // flight reads for step g+3 (LDS; chunk (g+3)/32 is staged)
            {
                const int gf = (g + 3 < LL) ? g + 3 : LL - 1;
                const int bf = (gf >> 5) % 3;
                const int sf = gf & 31;
                kr[(t + 3) & 3] = *(const float4*)&ks[bf][sf][e0];
                qr[(t + 3) & 3] = *(const float4*)&qs[bf][sf][e0];
                sr[(t + 3) & 3] = ss[bf][sf];
                vr[(t + 3) & 3] = vs_[bf][sf][rl];
            }
            const float4 kc = kr[t & 3];
            const float4 kn = kr[(t + 1) & 3];
            const float4 qc = qr[t & 3];
            const float4 sc = sr[t & 3];   // {alpha, beta, kk, qk}
            const float  vc = vr[t & 3];

            // S_{t-1}-dots (off the serial chain; red16 has a full iter of slack)
            float p0 = fmaf(S1, kn.y, S0 * kn.x);
            float p1 = fmaf(S3, kn.w, S2 * kn.z);
            float d1 = red16(p0 + p1);
            float u0 = fmaf(S1, qc.y, S0 * qc.x);
            float u1 = fmaf(S3, qc.w, S2 * qc.z);
            float d2 = red16(u0 + u1);

            // serial scalar chain
            const float cf = sc.y * fmaf(-sc.x, skc, vc);
            skc = fmaf(sc.x, d1, cf * sc.z);

            // state update
            S0 = fmaf(sc.x, S0, cf * kc.x);
            S1 = fmaf(sc.x, S1, cf * kc.y);
            S2 = fmaf(sc.x, S2, cf * kc.z);
            S3 = fmaf(sc.x, S3, cf * kc.w);

            // output
            const float o = fmaf(sc.x, d2, cf * sc.w);
            const int ph = t & 3;
            if (ph == 0) o0 = o;
            else if (ph == 1) o1 = o;
            else if (ph == 2) o2 = o;
            else if (el == 0)
                *(float4*)(op + g - 3) = make_float4(o0, o1, o2, o);
        }
        __syncthreads();   // drains chunk c+2 staging; buffers (c+1)%3 safe
    }
}

// ---------------------------------------------------------------------------
// Fused conv + transpose + split-f16 convert (unchanged from round 5).
// ---------------------------------------------------------------------------
__global__ __launch_bounds__(256) void conv_convert(
    const float* __restrict__ att, const float* __restrict__ Wconv,
    _Float16* __restrict__ Ae)
{
    __shared__ float yt[112][68];
    const int lb = blockIdx.x;
    const int h  = blockIdx.y;
    const int b  = blockIdx.z;
    const int tid = threadIdx.x;

    {
        const int d = tid >> 2;
        const int part = tid & 3;
        const float* src  = att + ((size_t)(b * NH + h) * DD + d) * LL;
        const float* srcm = src - (size_t)DD * LL;
        #pragma unroll
        for (int m = 0; m < 7; ++m) {
            const int off = (part * 7 + m) * 4;
            const int lg = lb * 64 - 48 + off;
            float4 v;
            if (lg >= 0)      v = *(const float4*)(src + lg);
            else if (h > 0)   v = *(const float4*)(srcm + lg + 1024);
            else              v = make_float4(0.f, 0.f, 0.f, 0.f);
            yt[off + 0][d] = v.x; yt[off + 1][d] = v.y;
            yt[off + 2][d] = v.z; yt[off + 3][d] = v.w;
        }
    }
    __syncthreads();

    float4 w[4];
    #pragma unroll
    for (int k = 0; k < 4; ++k)
        w[k] = ((const float4*)Wconv)[tid * 4 + k];

    const int d0 = (tid & 15) * 4;
    const int lq = tid >> 4;
    const float sc = 1.f / 4096.f;

    #pragma unroll
    for (int rr = 0; rr < 4; ++rr) {
        const int ll = rr * 16 + lq;
        float y0[4], y1[4], y2[4], y3[4];
        *(float4*)y0 = *(const float4*)&yt[ll +  0][d0];
        *(float4*)y1 = *(const float4*)&yt[ll + 16][d0];
        *(float4*)y2 = *(const float4*)&yt[ll + 32][d0];
        *(float4*)y3 = *(const float4*)&yt[ll + 48][d0];
        f16x4 hi, lo;
        #pragma unroll
        for (int k = 0; k < 4; ++k) {
            float acc = y3[k];
            acc = fmaf(w[k].x, y0[k], acc);
            acc = fmaf(w[k].y, y1[k], acc);
            acc = fmaf(w[k].z, y2[k], acc);
            acc = fmaf(w[k].w, y3[k], acc);
            acc *= sc;
            hi[k] = (_Float16)acc;
            lo[k] = (_Float16)(acc - (float)hi[k]);
        }
        const size_t row = (size_t)b * 1024 + h * 64 + lb * 4 + rr;
        _Float16* base = Ae + row * KEXT + tid * 4;
        *(f16x4*)(base)        = hi;
        *(f16x4*)(base + 1024) = lo;
        *(f16x4*)(base + 2048) = hi;
    }
}

// ---------------------------------------------------------------------------
extern "C" void kernel_launch(void* const* d_in, const int* in_sizes, int n_in,
                              void* d_out, int out_size, void* d_ws, size_t ws_size,
                              hipStream_t stream)
{
    const float* hs    = (const float*)d_in[0];
    const float* Wq    = (const float*)d_in[1];
    const float* bq    = (const float*)d_in[2];
    const float* Wk    = (const float*)d_in[3];
    const float* bk    = (const float*)d_in[4];
    const float* Wv    = (const float*)d_in[5];
    const float* bv    = (const float*)d_in[6];
    const float* Wa    = (const float*)d_in[7];
    const float* Wb    = (const float*)d_in[8];
    const float* Wconv = (const float*)d_in[9];
    const float* Wo    = (const float*)d_in[10];
    const float* bo    = (const float*)d_in[11];
    float* out = (float*)d_out;

    // workspace layout
    char* w = (char*)d_ws;
    float* qkv = (float*)w;        w += (size_t)MM * 3072 * 4;     // 25.2 MB
    float* att = (float*)w;        w += (size_t)MM * 1024 * 4;     //  8.4 MB ([B][NH][D][L])
    float* ab  = (float*)w;        w += (size_t)MM * 32 * 4;       //  0.26 MB
    float4* scal = (float4*)w;     w += (size_t)MM * 16 * 16;      //  0.52 MB
    _Float16* Ae = (_Float16*)w;   w += (size_t)MM * KEXT * 2;     // 12.6 MB
    _Float16* Be = (_Float16*)w;   w += (size_t)NB_QKV * KEXT * 2; // 19.7 MB

    // 1) split-f16 conversions for the fused qkv/alpha/beta GEMM
    hipLaunchKernelGGL(convert_A, dim3(MM), dim3(256), 0, stream, hs, Ae, 16.f);
    hipLaunchKernelGGL(convert_Wqkv, dim3(NB_QKV), dim3(256), 0, stream,
                       Wq, Wk, Wv, Wa, Wb, Be);

    // 2) fused q/k/v/alpha/beta projection via f16-split MFMA
    hipLaunchKernelGGL(mfma_gemm, dim3(NB_QKV / 128, MM / 128), dim3(256), 0, stream,
                       Ae, Be, qkv, ab, bq, bk, bv, (float*)nullptr, (const float*)nullptr, 0);

    // 3a) Gram/scalar pre-pass (alpha, beta, k.k_next, k.q per step)
    hipLaunchKernelGGL(gdn_dots, dim3(4, 32), dim3(256), 0, stream, qkv, ab, scal);

    // 3b) gated delta recurrence with lookahead (512 one-wave blocks)
    hipLaunchKernelGGL(gdn_recurrence, dim3(512), dim3(64), 0, stream, qkv, scal, att);

    // 4) fused conv + transpose + split-f16 convert (writes Ae for out-proj)
    hipLaunchKernelGGL(conv_convert, dim3(16, 16, BB), dim3(256), 0, stream,
                       att, Wconv, Ae);

    // 5) out-projection
    hipLaunchKernelGGL(convert_Wo, dim3(1024), dim3(256), 0, stream, Wo, Be);
    hipLaunchKernelGGL(mfma_gemm, dim3(1024 / 128, MM / 128), dim3(256), 0, stream,
                       Ae, Be, (float*)nullptr, (float*)nullptr,
                       (const float*)nullptr, (const float*)nullptr, (const float*)nullptr,
                       out, bo, 1);
}

// Round 7
// 354.296 us; speedup vs baseline: 1.1152x; 1.1152x over previous
//
#include <hip/hip_runtime.h>
#include <math.h>

// Problem constants
#define BB 2
#define LL 1024
#define HH 1024
#define NH 16
#define DD 64
#define HD (NH * DD)   // 1024
#define MM (BB * LL)   // 2048
#define RCT 32         // recurrence chunk length staged in LDS
#define KEXT 3072      // extended K for f16 hi/lo split GEMM (3 x 1024)
#define NB_QKV 3200    // Be rows: 3072 qkv + 32 alpha/beta + 96 zero pad

typedef _Float16 f16x8 __attribute__((ext_vector_type(8)));
typedef _Float16 f16x4 __attribute__((ext_vector_type(4)));
typedef float f32x4 __attribute__((ext_vector_type(4)));

// ---------------------------------------------------------------------------
// async global->LDS, 16B per lane; LDS dest = wave-uniform base + lane*16
// ---------------------------------------------------------------------------
__device__ __forceinline__ void load_lds16(const void* g, void* l) {
    __builtin_amdgcn_global_load_lds(
        (const __attribute__((address_space(1))) void*)g,
        (__attribute__((address_space(3))) void*)l, 16, 0, 0);
}

// ---------------------------------------------------------------------------
// Split-f16 conversion kernels. x = hi + lo captures ~22 mantissa bits.
// A-side along Kext: [hi | lo | hi]; B-side: [hi | hi | lo]
// => dot = hi*hi + lo*hi + hi*lo (missing lo*lo ~ 2^-22 rel).
// ---------------------------------------------------------------------------
__global__ __launch_bounds__(256) void convert_A(
    const float* __restrict__ X, _Float16* __restrict__ Ae, float scale)
{
    const int row = blockIdx.x;
    const int t = threadIdx.x;
    float4 x = *(const float4*)(X + (size_t)row * 1024 + t * 4);
    x.x *= scale; x.y *= scale; x.z *= scale; x.w *= scale;
    f16x4 h, l;
    h[0] = (_Float16)x.x; l[0] = (_Float16)(x.x - (float)h[0]);
    h[1] = (_Float16)x.y; l[1] = (_Float16)(x.y - (float)h[1]);
    h[2] = (_Float16)x.z; l[2] = (_Float16)(x.z - (float)h[2]);
    h[3] = (_Float16)x.w; l[3] = (_Float16)(x.w - (float)h[3]);
    _Float16* base = Ae + (size_t)row * KEXT + t * 4;
    *(f16x4*)(base)        = h;
    *(f16x4*)(base + 1024) = l;
    *(f16x4*)(base + 2048) = h;
}

__global__ __launch_bounds__(256) void convert_Wqkv(
    const float* __restrict__ Wq, const float* __restrict__ Wk,
    const float* __restrict__ Wv, const float* __restrict__ Wa,
    const float* __restrict__ Wb, _Float16* __restrict__ Be)
{
    const int n = blockIdx.x;
    const int t = threadIdx.x;
    const float* src = nullptr;
    if (n < 1024)      src = Wq + (size_t)n * 1024;
    else if (n < 2048) src = Wk + (size_t)(n - 1024) * 1024;
    else if (n < 3072) src = Wv + (size_t)(n - 2048) * 1024;
    else if (n < 3088) src = Wa + (size_t)(n - 3072) * 1024;
    else if (n < 3104) src = Wb + (size_t)(n - 3088) * 1024;
    float4 x = src ? *(const float4*)(src + t * 4) : make_float4(0.f,0.f,0.f,0.f);
    x.x *= 64.f; x.y *= 64.f; x.z *= 64.f; x.w *= 64.f;
    f16x4 h, l;
    h[0] = (_Float16)x.x; l[0] = (_Float16)(x.x - (float)h[0]);
    h[1] = (_Float16)x.y; l[1] = (_Float16)(x.y - (float)h[1]);
    h[2] = (_Float16)x.z; l[2] = (_Float16)(x.z - (float)h[2]);
    h[3] = (_Float16)x.w; l[3] = (_Float16)(x.w - (float)h[3]);
    _Float16* base = Be + (size_t)n * KEXT + t * 4;
    *(f16x4*)(base)        = h;
    *(f16x4*)(base + 1024) = h;
    *(f16x4*)(base + 2048) = l;
}

__global__ __launch_bounds__(256) void convert_Wo(
    const float* __restrict__ Wo, _Float16* __restrict__ Be)
{
    const int n = blockIdx.x;
    const int t = threadIdx.x;
    float4 x = *(const float4*)(Wo + (size_t)n * 1024 + t * 4);
    x.x *= 64.f; x.y *= 64.f; x.z *= 64.f; x.w *= 64.f;
    f16x4 h, l;
    h[0] = (_Float16)x.x; l[0] = (_Float16)(x.x - (float)h[0]);
    h[1] = (_Float16)x.y; l[1] = (_Float16)(x.y - (float)h[1]);
    h[2] = (_Float16)x.z; l[2] = (_Float16)(x.z - (float)h[2]);
    h[3] = (_Float16)x.w; l[3] = (_Float16)(x.w - (float)h[3]);
    _Float16* base = Be + (size_t)n * KEXT + t * 4;
    *(f16x4*)(base)        = h;
    *(f16x4*)(base + 1024) = h;
    *(f16x4*)(base + 2048) = l;
}

// ---------------------------------------------------------------------------
// MFMA GEMM, 128(M)x64(N) tile, BK=32, 256 thr = 4 waves (wave tile 64x32).
// Smaller N-tile -> 2x the blocks: out-proj 128->256 blocks (full device),
// qkv 400->800 blocks (kills the 1.56 blocks/CU tail). 12 KB LDS -> 4+
// blocks/CU co-residency.
// mode 0: epilogue scale 1/1024 -> qkv cols (+bias), cols 3072..3103 -> ab
//         with sigmoid/softplus. mode 1: scale 64, +bo -> out.
// ---------------------------------------------------------------------------
__global__ __launch_bounds__(256) void mfma_gemm(
    const _Float16* __restrict__ Ae, const _Float16* __restrict__ Be,
    float* __restrict__ qkv, float* __restrict__ ab,
    const float* __restrict__ bq, const float* __restrict__ bk,
    const float* __restrict__ bv,
    float* __restrict__ outp, const float* __restrict__ bo, int mode)
{
    __shared__ __align__(16) _Float16 As[128 * 32];
    __shared__ __align__(16) _Float16 Bs[64 * 32];

    const int tid = threadIdx.x;
    const int wave = tid >> 6;
    const int lane = tid & 63;
    const int bm = blockIdx.y * 128;
    const int bn = blockIdx.x * 64;
    const int wr = (wave >> 1) * 64;   // wave m-offset
    const int wc = (wave & 1) * 32;    // wave n-offset

    // staging: A) wave stages 32 rows (2 issues x 16 rows); B) 16 rows (1 issue)
    const int srow = lane >> 2;
    const int scol = (lane & 3) * 8;
    const _Float16* gA0 = Ae + (size_t)(bm + wave * 32 + srow) * KEXT + scol;
    const _Float16* gA1 = gA0 + (size_t)16 * KEXT;
    const _Float16* gB0 = Be + (size_t)(bn + wave * 16 + srow) * KEXT + scol;
    _Float16* lA0 = &As[(wave * 32) * 32];
    _Float16* lA1 = &As[(wave * 32 + 16) * 32];
    _Float16* lB0 = &Bs[(wave * 16) * 32];

    const int fm = lane & 15;
    const int fq = (lane >> 4) * 8;

    f32x4 acc[4][2] = {};

    for (int k0 = 0; k0 < KEXT; k0 += 32) {
        load_lds16(gA0 + k0, lA0);
        load_lds16(gA1 + k0, lA1);
        load_lds16(gB0 + k0, lB0);
        __syncthreads();

        f16x8 a[4], b[2];
        #pragma unroll
        for (int mt = 0; mt < 4; ++mt)
            a[mt] = *(const f16x8*)&As[(wr + mt * 16 + fm) * 32 + fq];
        #pragma unroll
        for (int nt = 0; nt < 2; ++nt)
            b[nt] = *(const f16x8*)&Bs[(wc + nt * 16 + fm) * 32 + fq];
        #pragma unroll
        for (int mt = 0; mt < 4; ++mt)
            #pragma unroll
            for (int nt = 0; nt < 2; ++nt)
                acc[mt][nt] = __builtin_amdgcn_mfma_f32_16x16x32_f16(
                    a[mt], b[nt], acc[mt][nt], 0, 0, 0);
        __syncthreads();
    }

    const int rquad = (lane >> 4) * 4;
    #pragma unroll
    for (int mt = 0; mt < 4; ++mt) {
        #pragma unroll
        for (int nt = 0; nt < 2; ++nt) {
            const int col = bn + wc + nt * 16 + fm;
            #pragma unroll
            for (int i = 0; i < 4; ++i) {
                const int row = bm + wr + mt * 16 + rquad + i;
                float val = acc[mt][nt][i];
                if (mode == 0) {
                    val *= (1.0f / 1024.0f);
                    if (col < 1024)
                        qkv[(size_t)row * 3072 + col] = val + bq[col];
                    else if (col < 2048)
                        qkv[(size_t)row * 3072 + col] = val + bk[col - 1024];
                    else if (col < 3072)
                        qkv[(size_t)row * 3072 + col] = val + bv[col - 2048];
                    else {
                        const int c = col - 3072;
                        if (c < 16)
                            ab[(size_t)row * 32 + c] = 1.f / (1.f + expf(-val));
                        else if (c < 32)
                            ab[(size_t)row * 32 + c] =
                                fmaxf(val, 0.f) + log1pf(expf(-fabsf(val)));
                    }
                } else {
                    outp[(size_t)row * 1024 + col] = val * 64.f + bo[col];
                }
            }
        }
    }
}

// ---------------------------------------------------------------------------
// DPP 16-lane reduction (xor1, xor2, row_ror:4, row_ror:8 -> all lanes hold sum)
// ---------------------------------------------------------------------------
template <int CTRL>
__device__ __forceinline__ float dpp_addf(float x) {
    int y = __builtin_amdgcn_update_dpp(0, __builtin_bit_cast(int, x),
                                        CTRL, 0xF, 0xF, true);
    return x + __builtin_bit_cast(float, y);
}
__device__ __forceinline__ float red16(float x) {
    x = dpp_addf<0xB1>(x);
    x = dpp_addf<0x4E>(x);
    x = dpp_addf<0x124>(x);
    x = dpp_addf<0x128>(x);
    return x;
}

// ---------------------------------------------------------------------------
// Gated delta recurrence (round-5 exact: 129 us known-good). 512 blocks x 64
// threads; blk%32 = chain (XCD co-location), blk/32 = row-slice of 4 rows.
// k/q staged via global_load_lds, double-buffered 32-step chunks; output att
// TRANSPOSED [B][NH][D][L], o accumulated 4 steps -> one float4 store.
// ---------------------------------------------------------------------------
__global__ __launch_bounds__(64) void gdn_recurrence(
    const float* __restrict__ qkv, const float* __restrict__ ab,
    float* __restrict__ att)
{
    __shared__ __align__(16) float ks[2][RCT][64];
    __shared__ __align__(16) float qs[2][RCT][64];
    __shared__ __align__(16) float vs_[2][RCT][4];
    __shared__ float gab[2][64];

    const int blk = blockIdx.x;
    const int bh = blk & 31;          // chain (XCD co-location)
    const int s  = blk >> 5;          // row-slice 0..15
    const int b  = bh >> 4;
    const int h  = bh & 15;
    const int lane = threadIdx.x;
    const int rl = lane >> 4;         // local row 0..3
    const int el = lane & 15;         // e-slice
    const int e0 = el * 4;
    const int r0 = s * 4;

    const float* qb  = qkv + (size_t)b * LL * 3072 + h * 64;
    const float* kb  = qb + 1024;
    const float* vb  = qb + 2048 + r0;
    const float* abp = ab + (size_t)b * LL * 32 + h;
    float* op = att + ((size_t)(b * NH + h) * DD + r0 + rl) * LL;

    const int st = lane >> 4;          // t-within-4 for staging
    const int sd = (lane & 15) * 4;    // d offset

    float S0 = 0.f, S1 = 0.f, S2 = 0.f, S3 = 0.f;

    // ---- async-stage k/q chunk 0, reg-load v/ab chunk 0 ----
    {
        const size_t ro = (size_t)st * 3072 + sd;
        #pragma unroll
        for (int m = 0; m < 8; ++m) {
            load_lds16(kb + ro + (size_t)m * 4 * 3072, &ks[0][m * 4][0]);
            load_lds16(qb + ro + (size_t)m * 4 * 3072, &qs[0][m * 4][0]);
        }
        float4 pv = make_float4(0.f,0.f,0.f,0.f);
        if (lane < RCT) pv = *(const float4*)(vb + (size_t)lane * 3072);
        float pab = (lane < 32) ? abp[(size_t)lane * 32]
                                : abp[(size_t)(lane - 32) * 32 + 16];
        if (lane < RCT) *(float4*)&vs_[0][lane][0] = pv;
        gab[0][lane] = pab;
    }
    __syncthreads();

    const int NCHUNK = LL / RCT;
    for (int c = 0; c < NCHUNK; ++c) {
        const int cur = c & 1, nxt = cur ^ 1;
        const bool more = (c + 1 < NCHUNK);

        // issue async staging for chunk c+1; tiny reg prefetch for v/ab
        float4 pv = make_float4(0.f,0.f,0.f,0.f);
        float pab = 0.f;
        if (more) {
            const size_t t0 = (size_t)(c + 1) * RCT;
            const size_t ro = (t0 + st) * 3072 + sd;
            #pragma unroll
            for (int m = 0; m < 8; ++m) {
                load_lds16(kb + ro + (size_t)m * 4 * 3072, &ks[nxt][m * 4][0]);
                load_lds16(qb + ro + (size_t)m * 4 * 3072, &qs[nxt][m * 4][0]);
            }
            if (lane < RCT) pv = *(const float4*)(vb + (t0 + lane) * 3072);
            pab = (lane < 32) ? abp[(t0 + lane) * 32]
                              : abp[(t0 + lane - 32) * 32 + 16];
        }

        // ---- 32 steps from buffer cur, 1-step LDS->reg prefetch ----
        float4 kc = *(const float4*)&ks[cur][0][e0];
        float4 qc = *(const float4*)&qs[cur][0][e0];
        float vc = vs_[cur][0][rl];
        float ac = gab[cur][0];
        float bc = gab[cur][32];

        float o0 = 0.f, o1 = 0.f, o2 = 0.f;
        #pragma unroll 4
        for (int t = 0; t < RCT; ++t) {
            const int tn = (t + 1) & (RCT - 1);
            float4 kn = *(const float4*)&ks[cur][tn][e0];
            float4 qn = *(const float4*)&qs[cur][tn][e0];
            const float vn  = vs_[cur][tn][rl];
            const float an  = gab[cur][tn];
            const float bn2 = gab[cur][32 + tn];

            // sk = (S . k) row-dot
            float p0 = fmaf(S1, kc.y, S0 * kc.x);
            float p1 = fmaf(S3, kc.w, S2 * kc.z);
            float sk = red16(p0 + p1);

            const float cf = bc * fmaf(-ac, sk, vc);

            S0 = fmaf(ac, S0, cf * kc.x);
            S1 = fmaf(ac, S1, cf * kc.y);
            S2 = fmaf(ac, S2, cf * kc.z);
            S3 = fmaf(ac, S3, cf * kc.w);

            float q0 = fmaf(S1, qc.y, S0 * qc.x);
            float q1 = fmaf(S3, qc.w, S2 * qc.z);
            float o = red16(q0 + q1);

            const int ph = t & 3;
            if (ph == 0) o0 = o;
            else if (ph == 1) o1 = o;
            else if (ph == 2) o2 = o;
            else if (el == 0)
                *(float4*)(op + c * RCT + t - 3) = make_float4(o0, o1, o2, o);

            kc = kn; qc = qn; vc = vn; ac = an; bc = bn2;
        }

        // commit v/ab prefetch into next buffer, then publish
        if (more) {
            if (lane < RCT) *(float4*)&vs_[nxt][lane][0] = pv;
            gab[nxt][lane] = pab;
        }
        __syncthreads();
    }
}

// ---------------------------------------------------------------------------
// Fused: residual depthwise causal conv (bug-compat reshaped view) +
// transpose back + split-f16 convert for the out-projection A matrix.
// ---------------------------------------------------------------------------
__global__ __launch_bounds__(256) void conv_convert(
    const float* __restrict__ att, const float* __restrict__ Wconv,
    _Float16* __restrict__ Ae)
{
    __shared__ float yt[112][68];
    const int lb = blockIdx.x;
    const int h  = blockIdx.y;
    const int b  = blockIdx.z;
    const int tid = threadIdx.x;

    {
        const int d = tid >> 2;
        const int part = tid & 3;
        const float* src  = att + ((size_t)(b * NH + h) * DD + d) * LL;
        const float* srcm = src - (size_t)DD * LL;
        #pragma unroll
        for (int m = 0; m < 7; ++m) {
            const int off = (part * 7 + m) * 4;
            const int lg = lb * 64 - 48 + off;
            float4 v;
            if (lg >= 0)      v = *(const float4*)(src + lg);
            else if (h > 0)   v = *(const float4*)(srcm + lg + 1024);
            else              v = make_float4(0.f, 0.f, 0.f, 0.f);
            yt[off + 0][d] = v.x; yt[off + 1][d] = v.y;
            yt[off + 2][d] = v.z; yt[off + 3][d] = v.w;
        }
    }
    __syncthreads();

    float4 w[4];
    #pragma unroll
    for (int k = 0; k < 4; ++k)
        w[k] = ((const float4*)Wconv)[tid * 4 + k];

    const int d0 = (tid & 15) * 4;
    const int lq = tid >> 4;
    const float sc = 1.f / 4096.f;

    #pragma unroll
    for (int rr = 0; rr < 4; ++rr) {
        const int ll = rr * 16 + lq;
        float y0[4], y1[4], y2[4], y3[4];
        *(float4*)y0 = *(const float4*)&yt[ll +  0][d0];
        *(float4*)y1 = *(const float4*)&yt[ll + 16][d0];
        *(float4*)y2 = *(const float4*)&yt[ll + 32][d0];
        *(float4*)y3 = *(const float4*)&yt[ll + 48][d0];
        f16x4 hi, lo;
        #pragma unroll
        for (int k = 0; k < 4; ++k) {
            float acc = y3[k];
            acc = fmaf(w[k].x, y0[k], acc);
            acc = fmaf(w[k].y, y1[k], acc);
            acc = fmaf(w[k].z, y2[k], acc);
            acc = fmaf(w[k].w, y3[k], acc);
            acc *= sc;
            hi[k] = (_Float16)acc;
            lo[k] = (_Float16)(acc - (float)hi[k]);
        }
        const size_t row = (size_t)b * 1024 + h * 64 + lb * 4 + rr;
        _Float16* base = Ae + row * KEXT + tid * 4;
        *(f16x4*)(base)        = hi;
        *(f16x4*)(base + 1024) = lo;
        *(f16x4*)(base + 2048) = hi;
    }
}

// ---------------------------------------------------------------------------
extern "C" void kernel_launch(void* const* d_in, const int* in_sizes, int n_in,
                              void* d_out, int out_size, void* d_ws, size_t ws_size,
                              hipStream_t stream)
{
    const float* hs    = (const float*)d_in[0];
    const float* Wq    = (const float*)d_in[1];
    const float* bq    = (const float*)d_in[2];
    const float* Wk    = (const float*)d_in[3];
    const float* bk    = (const float*)d_in[4];
    const float* Wv    = (const float*)d_in[5];
    const float* bv    = (const float*)d_in[6];
    const float* Wa    = (const float*)d_in[7];
    const float* Wb    = (const float*)d_in[8];
    const float* Wconv = (const float*)d_in[9];
    const float* Wo    = (const float*)d_in[10];
    const float* bo    = (const float*)d_in[11];
    float* out = (float*)d_out;

    // workspace layout
    char* w = (char*)d_ws;
    float* qkv = (float*)w;        w += (size_t)MM * 3072 * 4;     // 25.2 MB
    float* att = (float*)w;        w += (size_t)MM * 1024 * 4;     //  8.4 MB ([B][NH][D][L])
    float* ab  = (float*)w;        w += (size_t)MM * 32 * 4;       //  0.26 MB
    _Float16* Ae = (_Float16*)w;   w += (size_t)MM * KEXT * 2;     // 12.6 MB
    _Float16* Be = (_Float16*)w;   w += (size_t)NB_QKV * KEXT * 2; // 19.7 MB

    // 1) split-f16 conversions for the fused qkv/alpha/beta GEMM
    hipLaunchKernelGGL(convert_A, dim3(MM), dim3(256), 0, stream, hs, Ae, 16.f);
    hipLaunchKernelGGL(convert_Wqkv, dim3(NB_QKV), dim3(256), 0, stream,
                       Wq, Wk, Wv, Wa, Wb, Be);

    // 2) fused q/k/v/alpha/beta projection via f16-split MFMA (128x64 tiles)
    hipLaunchKernelGGL(mfma_gemm, dim3(NB_QKV / 64, MM / 128), dim3(256), 0, stream,
                       Ae, Be, qkv, ab, bq, bk, bv, (float*)nullptr, (const float*)nullptr, 0);

    // 3) gated delta recurrence (round-5 exact, 512 one-wave blocks)
    hipLaunchKernelGGL(gdn_recurrence, dim3(512), dim3(64), 0, stream, qkv, ab, att);

    // 4) fused conv + transpose + split-f16 convert (writes Ae for out-proj)
    hipLaunchKernelGGL(conv_convert, dim3(16, 16, BB), dim3(256), 0, stream,
                       att, Wconv, Ae);

    // 5) out-projection (128x64 tiles -> 256 blocks, full device)
    hipLaunchKernelGGL(convert_Wo, dim3(1024), dim3(256), 0, stream, Wo, Be);
    hipLaunchKernelGGL(mfma_gemm, dim3(1024 / 64, MM / 128), dim3(256), 0, stream,
                       Ae, Be, (float*)nullptr, (float*)nullptr,
                       (const float*)nullptr, (const float*)nullptr, (const float*)nullptr,
                       out, bo, 1);
}

// Round 8
// 344.078 us; speedup vs baseline: 1.1483x; 1.0297x over previous
//
#include <hip/hip_runtime.h>
#include <math.h>

// Problem constants
#define BB 2
#define LL 1024
#define HH 1024
#define NH 16
#define DD 64
#define HD (NH * DD)   // 1024
#define MM (BB * LL)   // 2048
#define RCT 32         // recurrence chunk length staged in LDS
#define KEXT 3072      // extended K for f16 hi/lo split GEMM (3 x 1024)
#define NB_QKV 3200    // Be rows: 3072 qkv + 32 alpha/beta + 96 zero pad

typedef _Float16 f16x8 __attribute__((ext_vector_type(8)));
typedef _Float16 f16x4 __attribute__((ext_vector_type(4)));
typedef float f32x4 __attribute__((ext_vector_type(4)));

// ---------------------------------------------------------------------------
// async global->LDS, 16B per lane; LDS dest = wave-uniform base + lane*16
// ---------------------------------------------------------------------------
__device__ __forceinline__ void load_lds16(const void* g, void* l) {
    __builtin_amdgcn_global_load_lds(
        (const __attribute__((address_space(1))) void*)g,
        (__attribute__((address_space(3))) void*)l, 16, 0, 0);
}

// ---------------------------------------------------------------------------
// Split-f16 conversions. x = hi + lo captures ~22 mantissa bits.
// A-side along Kext: [hi | lo | hi]; B-side: [hi | hi | lo]
// => dot = hi*hi + lo*hi + hi*lo (missing lo*lo ~ 2^-22 rel).
// Merged kernel: blocks 0..2047 convert hs rows (scale 16) -> Ae;
// blocks 2048..5247 convert W rows (scale 64) -> Be.
// ---------------------------------------------------------------------------
__global__ __launch_bounds__(256) void convert_front(
    const float* __restrict__ hs,
    const float* __restrict__ Wq, const float* __restrict__ Wk,
    const float* __restrict__ Wv, const float* __restrict__ Wa,
    const float* __restrict__ Wb,
    _Float16* __restrict__ Ae, _Float16* __restrict__ Be)
{
    const int blk = blockIdx.x;
    const int t = threadIdx.x;
    const float* src = nullptr;
    _Float16* dst;
    float scale;
    bool a_side;
    if (blk < 2048) {
        src = hs + (size_t)blk * 1024;
        dst = Ae + (size_t)blk * KEXT;
        scale = 16.f; a_side = true;
    } else {
        const int n = blk - 2048;
        if (n < 1024)      src = Wq + (size_t)n * 1024;
        else if (n < 2048) src = Wk + (size_t)(n - 1024) * 1024;
        else if (n < 3072) src = Wv + (size_t)(n - 2048) * 1024;
        else if (n < 3088) src = Wa + (size_t)(n - 3072) * 1024;
        else if (n < 3104) src = Wb + (size_t)(n - 3088) * 1024;
        dst = Be + (size_t)n * KEXT;
        scale = 64.f; a_side = false;
    }
    float4 x = src ? *(const float4*)(src + t * 4) : make_float4(0.f,0.f,0.f,0.f);
    x.x *= scale; x.y *= scale; x.z *= scale; x.w *= scale;
    f16x4 h, l;
    h[0] = (_Float16)x.x; l[0] = (_Float16)(x.x - (float)h[0]);
    h[1] = (_Float16)x.y; l[1] = (_Float16)(x.y - (float)h[1]);
    h[2] = (_Float16)x.z; l[2] = (_Float16)(x.z - (float)h[2]);
    h[3] = (_Float16)x.w; l[3] = (_Float16)(x.w - (float)h[3]);
    _Float16* base = dst + t * 4;
    *(f16x4*)(base)        = h;
    *(f16x4*)(base + 1024) = a_side ? l : h;
    *(f16x4*)(base + 2048) = a_side ? h : l;
}

__global__ __launch_bounds__(256) void convert_Wo(
    const float* __restrict__ Wo, _Float16* __restrict__ Be)
{
    const int n = blockIdx.x;
    const int t = threadIdx.x;
    float4 x = *(const float4*)(Wo + (size_t)n * 1024 + t * 4);
    x.x *= 64.f; x.y *= 64.f; x.z *= 64.f; x.w *= 64.f;
    f16x4 h, l;
    h[0] = (_Float16)x.x; l[0] = (_Float16)(x.x - (float)h[0]);
    h[1] = (_Float16)x.y; l[1] = (_Float16)(x.y - (float)h[1]);
    h[2] = (_Float16)x.z; l[2] = (_Float16)(x.z - (float)h[2]);
    h[3] = (_Float16)x.w; l[3] = (_Float16)(x.w - (float)h[3]);
    _Float16* base = Be + (size_t)n * KEXT + t * 4;
    *(f16x4*)(base)        = h;
    *(f16x4*)(base + 1024) = h;
    *(f16x4*)(base + 2048) = l;
}

// ---------------------------------------------------------------------------
// MFMA GEMM, 128(M)x64(N) tile, BK=64 (two 32-wide k-slices per barrier
// pair -> halves barrier crossings per MFMA vs BK=32). 256 thr = 4 waves,
// wave tile 64x32. LDS 24 KB.
// mode 0: epilogue scale 1/1024 -> qkv cols (+bias), cols 3072..3103 -> ab
//         with sigmoid/softplus. mode 1: scale 64, +bo -> out.
// ---------------------------------------------------------------------------
__global__ __launch_bounds__(256) void mfma_gemm(
    const _Float16* __restrict__ Ae, const _Float16* __restrict__ Be,
    float* __restrict__ qkv, float* __restrict__ ab,
    const float* __restrict__ bq, const float* __restrict__ bk,
    const float* __restrict__ bv,
    float* __restrict__ outp, const float* __restrict__ bo, int mode)
{
    __shared__ __align__(16) _Float16 As[2][128 * 32];
    __shared__ __align__(16) _Float16 Bs[2][64 * 32];

    const int tid = threadIdx.x;
    const int wave = tid >> 6;
    const int lane = tid & 63;
    const int bm = blockIdx.y * 128;
    const int bn = blockIdx.x * 64;
    const int wr = (wave >> 1) * 64;   // wave m-offset
    const int wc = (wave & 1) * 32;    // wave n-offset

    const int srow = lane >> 2;
    const int scol = (lane & 3) * 8;
    const _Float16* gA0 = Ae + (size_t)(bm + wave * 32 + srow) * KEXT + scol;
    const _Float16* gA1 = gA0 + (size_t)16 * KEXT;
    const _Float16* gB0 = Be + (size_t)(bn + wave * 16 + srow) * KEXT + scol;
    _Float16* lA0_0 = &As[0][(wave * 32) * 32];
    _Float16* lA1_0 = &As[0][(wave * 32 + 16) * 32];
    _Float16* lB0_0 = &Bs[0][(wave * 16) * 32];
    _Float16* lA0_1 = &As[1][(wave * 32) * 32];
    _Float16* lA1_1 = &As[1][(wave * 32 + 16) * 32];
    _Float16* lB0_1 = &Bs[1][(wave * 16) * 32];

    const int fm = lane & 15;
    const int fq = (lane >> 4) * 8;

    f32x4 acc[4][2] = {};

    for (int k0 = 0; k0 < KEXT; k0 += 64) {
        load_lds16(gA0 + k0,      lA0_0);
        load_lds16(gA1 + k0,      lA1_0);
        load_lds16(gB0 + k0,      lB0_0);
        load_lds16(gA0 + k0 + 32, lA0_1);
        load_lds16(gA1 + k0 + 32, lA1_1);
        load_lds16(gB0 + k0 + 32, lB0_1);
        __syncthreads();

        #pragma unroll
        for (int s = 0; s < 2; ++s) {
            f16x8 a[4], b[2];
            #pragma unroll
            for (int mt = 0; mt < 4; ++mt)
                a[mt] = *(const f16x8*)&As[s][(wr + mt * 16 + fm) * 32 + fq];
            #pragma unroll
            for (int nt = 0; nt < 2; ++nt)
                b[nt] = *(const f16x8*)&Bs[s][(wc + nt * 16 + fm) * 32 + fq];
            #pragma unroll
            for (int mt = 0; mt < 4; ++mt)
                #pragma unroll
                for (int nt = 0; nt < 2; ++nt)
                    acc[mt][nt] = __builtin_amdgcn_mfma_f32_16x16x32_f16(
                        a[mt], b[nt], acc[mt][nt], 0, 0, 0);
        }
        __syncthreads();
    }

    const int rquad = (lane >> 4) * 4;
    #pragma unroll
    for (int mt = 0; mt < 4; ++mt) {
        #pragma unroll
        for (int nt = 0; nt < 2; ++nt) {
            const int col = bn + wc + nt * 16 + fm;
            #pragma unroll
            for (int i = 0; i < 4; ++i) {
                const int row = bm + wr + mt * 16 + rquad + i;
                float val = acc[mt][nt][i];
                if (mode == 0) {
                    val *= (1.0f / 1024.0f);
                    if (col < 1024)
                        qkv[(size_t)row * 3072 + col] = val + bq[col];
                    else if (col < 2048)
                        qkv[(size_t)row * 3072 + col] = val + bk[col - 1024];
                    else if (col < 3072)
                        qkv[(size_t)row * 3072 + col] = val + bv[col - 2048];
                    else {
                        const int c = col - 3072;
                        if (c < 16)
                            ab[(size_t)row * 32 + c] = 1.f / (1.f + expf(-val));
                        else if (c < 32)
                            ab[(size_t)row * 32 + c] =
                                fmaxf(val, 0.f) + log1pf(expf(-fabsf(val)));
                    }
                } else {
                    outp[(size_t)row * 1024 + col] = val * 64.f + bo[col];
                }
            }
        }
    }
}

// ---------------------------------------------------------------------------
// DPP 16-lane reduction (xor1, xor2, row_ror:4, row_ror:8 -> all lanes hold sum)
// ---------------------------------------------------------------------------
template <int CTRL>
__device__ __forceinline__ float dpp_addf(float x) {
    int y = __builtin_amdgcn_update_dpp(0, __builtin_bit_cast(int, x),
                                        CTRL, 0xF, 0xF, true);
    return x + __builtin_bit_cast(float, y);
}
__device__ __forceinline__ float red16(float x) {
    x = dpp_addf<0xB1>(x);
    x = dpp_addf<0x4E>(x);
    x = dpp_addf<0x124>(x);
    x = dpp_addf<0x128>(x);
    return x;
}

// ---------------------------------------------------------------------------
// Gated delta recurrence (r5 structure; only change: alpha/beta packed as
// float2 -> one ds_read_b64/step instead of two ds_read_b32). 512 blocks x
// 64 threads; blk%32 = chain (XCD co-location), blk/32 = 4-row slice.
// ---------------------------------------------------------------------------
__global__ __launch_bounds__(64) void gdn_recurrence(
    const float* __restrict__ qkv, const float* __restrict__ ab,
    float* __restrict__ att)
{
    __shared__ __align__(16) float ks[2][RCT][64];
    __shared__ __align__(16) float qs[2][RCT][64];
    __shared__ __align__(16) float vs_[2][RCT][4];
    __shared__ __align__(16) float gab[2][RCT][2];

    const int blk = blockIdx.x;
    const int bh = blk & 31;          // chain (XCD co-location)
    const int s  = blk >> 5;          // row-slice 0..15
    const int b  = bh >> 4;
    const int h  = bh & 15;
    const int lane = threadIdx.x;
    const int rl = lane >> 4;         // local row 0..3
    const int el = lane & 15;         // e-slice
    const int e0 = el * 4;
    const int r0 = s * 4;

    const float* qb  = qkv + (size_t)b * LL * 3072 + h * 64;
    const float* kb  = qb + 1024;
    const float* vb  = qb + 2048 + r0;
    const float* abp = ab + (size_t)b * LL * 32 + h;
    float* op = att + ((size_t)(b * NH + h) * DD + r0 + rl) * LL;

    const int st = lane >> 4;          // t-within-4 for staging
    const int sd = (lane & 15) * 4;    // d offset

    float S0 = 0.f, S1 = 0.f, S2 = 0.f, S3 = 0.f;

    // ---- async-stage k/q chunk 0, reg-load v/ab chunk 0 ----
    {
        const size_t ro = (size_t)st * 3072 + sd;
        #pragma unroll
        for (int m = 0; m < 8; ++m) {
            load_lds16(kb + ro + (size_t)m * 4 * 3072, &ks[0][m * 4][0]);
            load_lds16(qb + ro + (size_t)m * 4 * 3072, &qs[0][m * 4][0]);
        }
        float4 pv = make_float4(0.f,0.f,0.f,0.f);
        if (lane < RCT) pv = *(const float4*)(vb + (size_t)lane * 3072);
        float pab = (lane < 32) ? abp[(size_t)lane * 32]
                                : abp[(size_t)(lane - 32) * 32 + 16];
        if (lane < RCT) *(float4*)&vs_[0][lane][0] = pv;
        if (lane < 32) gab[0][lane][0] = pab;
        else           gab[0][lane - 32][1] = pab;
    }
    __syncthreads();

    const int NCHUNK = LL / RCT;
    for (int c = 0; c < NCHUNK; ++c) {
        const int cur = c & 1, nxt = cur ^ 1;
        const bool more = (c + 1 < NCHUNK);

        // issue async staging for chunk c+1; tiny reg prefetch for v/ab
        float4 pv = make_float4(0.f,0.f,0.f,0.f);
        float pab = 0.f;
        if (more) {
            const size_t t0 = (size_t)(c + 1) * RCT;
            const size_t ro = (t0 + st) * 3072 + sd;
            #pragma unroll
            for (int m = 0; m < 8; ++m) {
                load_lds16(kb + ro + (size_t)m * 4 * 3072, &ks[nxt][m * 4][0]);
                load_lds16(qb + ro + (size_t)m * 4 * 3072, &qs[nxt][m * 4][0]);
            }
            if (lane < RCT) pv = *(const float4*)(vb + (t0 + lane) * 3072);
            pab = (lane < 32) ? abp[(t0 + lane) * 32]
                              : abp[(t0 + lane - 32) * 32 + 16];
        }

        // ---- 32 steps from buffer cur, 1-step LDS->reg prefetch ----
        float4 kc = *(const float4*)&ks[cur][0][e0];
        float4 qc = *(const float4*)&qs[cur][0][e0];
        float vc = vs_[cur][0][rl];
        float2 abc = *(const float2*)&gab[cur][0][0];
        float ac = abc.x;
        float bc = abc.y;

        float o0 = 0.f, o1 = 0.f, o2 = 0.f;
        #pragma unroll 4
        for (int t = 0; t < RCT; ++t) {
            const int tn = (t + 1) & (RCT - 1);
            float4 kn = *(const float4*)&ks[cur][tn][e0];
            float4 qn = *(const float4*)&qs[cur][tn][e0];
            const float vn = vs_[cur][tn][rl];
            const float2 abn = *(const float2*)&gab[cur][tn][0];

            // sk = (S . k) row-dot
            float p0 = fmaf(S1, kc.y, S0 * kc.x);
            float p1 = fmaf(S3, kc.w, S2 * kc.z);
            float sk = red16(p0 + p1);

            const float cf = bc * fmaf(-ac, sk, vc);

            S0 = fmaf(ac, S0, cf * kc.x);
            S1 = fmaf(ac, S1, cf * kc.y);
            S2 = fmaf(ac, S2, cf * kc.z);
            S3 = fmaf(ac, S3, cf * kc.w);

            float q0 = fmaf(S1, qc.y, S0 * qc.x);
            float q1 = fmaf(S3, qc.w, S2 * qc.z);
            float o = red16(q0 + q1);

            const int ph = t & 3;
            if (ph == 0) o0 = o;
            else if (ph == 1) o1 = o;
            else if (ph == 2) o2 = o;
            else if (el == 0)
                *(float4*)(op + c * RCT + t - 3) = make_float4(o0, o1, o2, o);

            kc = kn; qc = qn; vc = vn; ac = abn.x; bc = abn.y;
        }

        // commit v/ab prefetch into next buffer, then publish
        if (more) {
            if (lane < RCT) *(float4*)&vs_[nxt][lane][0] = pv;
            if (lane < 32) gab[nxt][lane][0] = pab;
            else           gab[nxt][lane - 32][1] = pab;
        }
        __syncthreads();
    }
}

// ---------------------------------------------------------------------------
// Fused: residual depthwise causal conv (bug-compat reshaped view) +
// transpose back + split-f16 convert for the out-projection A matrix.
// ---------------------------------------------------------------------------
__global__ __launch_bounds__(256) void conv_convert(
    const float* __restrict__ att, const float* __restrict__ Wconv,
    _Float16* __restrict__ Ae)
{
    __shared__ float yt[112][68];
    const int lb = blockIdx.x;
    const int h  = blockIdx.y;
    const int b  = blockIdx.z;
    const int tid = threadIdx.x;

    {
        const int d = tid >> 2;
        const int part = tid & 3;
        const float* src  = att + ((size_t)(b * NH + h) * DD + d) * LL;
        const float* srcm = src - (size_t)DD * LL;
        #pragma unroll
        for (int m = 0; m < 7; ++m) {
            const int off = (part * 7 + m) * 4;
            const int lg = lb * 64 - 48 + off;
            float4 v;
            if (lg >= 0)      v = *(const float4*)(src + lg);
            else if (h > 0)   v = *(const float4*)(srcm + lg + 1024);
            else              v = make_float4(0.f, 0.f, 0.f, 0.f);
            yt[off + 0][d] = v.x; yt[off + 1][d] = v.y;
            yt[off + 2][d] = v.z; yt[off + 3][d] = v.w;
        }
    }
    __syncthreads();

    float4 w[4];
    #pragma unroll
    for (int k = 0; k < 4; ++k)
        w[k] = ((const float4*)Wconv)[tid * 4 + k];

    const int d0 = (tid & 15) * 4;
    const int lq = tid >> 4;
    const float sc = 1.f / 4096.f;

    #pragma unroll
    for (int rr = 0; rr < 4; ++rr) {
        const int ll = rr * 16 + lq;
        float y0[4], y1[4], y2[4], y3[4];
        *(float4*)y0 = *(const float4*)&yt[ll +  0][d0];
        *(float4*)y1 = *(const float4*)&yt[ll + 16][d0];
        *(float4*)y2 = *(const float4*)&yt[ll + 32][d0];
        *(float4*)y3 = *(const float4*)&yt[ll + 48][d0];
        f16x4 hi, lo;
        #pragma unroll
        for (int k = 0; k < 4; ++k) {
            float acc = y3[k];
            acc = fmaf(w[k].x, y0[k], acc);
            acc = fmaf(w[k].y, y1[k], acc);
            acc = fmaf(w[k].z, y2[k], acc);
            acc = fmaf(w[k].w, y3[k], acc);
            acc *= sc;
            hi[k] = (_Float16)acc;
            lo[k] = (_Float16)(acc - (float)hi[k]);
        }
        const size_t row = (size_t)b * 1024 + h * 64 + lb * 4 + rr;
        _Float16* base = Ae + row * KEXT + tid * 4;
        *(f16x4*)(base)        = hi;
        *(f16x4*)(base + 1024) = lo;
        *(f16x4*)(base + 2048) = hi;
    }
}

// ---------------------------------------------------------------------------
extern "C" void kernel_launch(void* const* d_in, const int* in_sizes, int n_in,
                              void* d_out, int out_size, void* d_ws, size_t ws_size,
                              hipStream_t stream)
{
    const float* hs    = (const float*)d_in[0];
    const float* Wq    = (const float*)d_in[1];
    const float* bq    = (const float*)d_in[2];
    const float* Wk    = (const float*)d_in[3];
    const float* bk    = (const float*)d_in[4];
    const float* Wv    = (const float*)d_in[5];
    const float* bv    = (const float*)d_in[6];
    const float* Wa    = (const float*)d_in[7];
    const float* Wb    = (const float*)d_in[8];
    const float* Wconv = (const float*)d_in[9];
    const float* Wo    = (const float*)d_in[10];
    const float* bo    = (const float*)d_in[11];
    float* out = (float*)d_out;

    // workspace layout
    char* w = (char*)d_ws;
    float* qkv = (float*)w;        w += (size_t)MM * 3072 * 4;     // 25.2 MB
    float* att = (float*)w;        w += (size_t)MM * 1024 * 4;     //  8.4 MB ([B][NH][D][L])
    float* ab  = (float*)w;        w += (size_t)MM * 32 * 4;       //  0.26 MB
    _Float16* Ae = (_Float16*)w;   w += (size_t)MM * KEXT * 2;     // 12.6 MB
    _Float16* Be = (_Float16*)w;   w += (size_t)NB_QKV * KEXT * 2; // 19.7 MB

    // 1) merged split-f16 conversions (hs -> Ae, W* -> Be)
    hipLaunchKernelGGL(convert_front, dim3(2048 + NB_QKV), dim3(256), 0, stream,
                       hs, Wq, Wk, Wv, Wa, Wb, Ae, Be);

    // 2) fused q/k/v/alpha/beta projection via f16-split MFMA (128x64, BK=64)
    hipLaunchKernelGGL(mfma_gemm, dim3(NB_QKV / 64, MM / 128), dim3(256), 0, stream,
                       Ae, Be, qkv, ab, bq, bk, bv, (float*)nullptr, (const float*)nullptr, 0);

    // 3) out-proj weight convert (Be region is dead after qkv GEMM)
    hipLaunchKernelGGL(convert_Wo, dim3(1024), dim3(256), 0, stream, Wo, Be);

    // 4) gated delta recurrence (r5 structure + ab-pack, 512 one-wave blocks)
    hipLaunchKernelGGL(gdn_recurrence, dim3(512), dim3(64), 0, stream, qkv, ab, att);

    // 5) fused conv + transpose + split-f16 convert (writes Ae for out-proj)
    hipLaunchKernelGGL(conv_convert, dim3(16, 16, BB), dim3(256), 0, stream,
                       att, Wconv, Ae);

    // 6) out-projection (128x64, BK=64 -> 256 blocks, full device)
    hipLaunchKernelGGL(mfma_gemm, dim3(1024 / 64, MM / 128), dim3(256), 0, stream,
                       Ae, Be, (float*)nullptr, (float*)nullptr,
                       (const float*)nullptr, (const float*)nullptr, (const float*)nullptr,
                       out, bo, 1);
}

// Round 9
// 307.391 us; speedup vs baseline: 1.2854x; 1.1193x over previous
//
#include <hip/hip_runtime.h>
#include <math.h>

// Problem constants
#define BB 2
#define LL 1024
#define HH 1024
#define NH 16
#define DD 64
#define HD (NH * DD)   // 1024
#define MM (BB * LL)   // 2048
#define RCT 32         // recurrence chunk length staged in LDS
#define KEXT 3072      // extended K for f16 hi/lo split GEMM (3 x 1024)
#define NB_QKV 3200    // Be rows: 3072 qkv + 32 alpha/beta + 96 zero pad

typedef _Float16 f16x8 __attribute__((ext_vector_type(8)));
typedef _Float16 f16x4 __attribute__((ext_vector_type(4)));
typedef float f32x4 __attribute__((ext_vector_type(4)));

// ---------------------------------------------------------------------------
// async global->LDS, 16B per lane; LDS dest = wave-uniform base + lane*16
// ---------------------------------------------------------------------------
__device__ __forceinline__ void load_lds16(const void* g, void* l) {
    __builtin_amdgcn_global_load_lds(
        (const __attribute__((address_space(1))) void*)g,
        (__attribute__((address_space(3))) void*)l, 16, 0, 0);
}

// ---------------------------------------------------------------------------
// Split-f16 conversions. x = hi + lo captures ~22 mantissa bits.
// A-side along Kext: [hi | lo | hi]; B-side: [hi | hi | lo]
// => dot = hi*hi + lo*hi + hi*lo (missing lo*lo ~ 2^-22 rel).
// Merged: blocks [0,2048) hs->Ae (x16, 3-split); [2048,5248) W*->Be (x64,
// 3-split); [5248,6272) Wo->Be2 (x64, hi-only — out-proj runs plain f16,
// its error is not recurrence-amplified).
// ---------------------------------------------------------------------------
__global__ __launch_bounds__(256) void convert_front(
    const float* __restrict__ hs,
    const float* __restrict__ Wq, const float* __restrict__ Wk,
    const float* __restrict__ Wv, const float* __restrict__ Wa,
    const float* __restrict__ Wb, const float* __restrict__ Wo,
    _Float16* __restrict__ Ae, _Float16* __restrict__ Be,
    _Float16* __restrict__ Be2)
{
    const int blk = blockIdx.x;
    const int t = threadIdx.x;

    if (blk >= 5248) {   // Wo -> Be2, hi only
        const int n = blk - 5248;
        float4 x = *(const float4*)(Wo + (size_t)n * 1024 + t * 4);
        f16x4 h;
        h[0] = (_Float16)(x.x * 64.f);
        h[1] = (_Float16)(x.y * 64.f);
        h[2] = (_Float16)(x.z * 64.f);
        h[3] = (_Float16)(x.w * 64.f);
        *(f16x4*)(Be2 + (size_t)n * 1024 + t * 4) = h;
        return;
    }

    const float* src = nullptr;
    _Float16* dst;
    float scale;
    bool a_side;
    if (blk < 2048) {
        src = hs + (size_t)blk * 1024;
        dst = Ae + (size_t)blk * KEXT;
        scale = 16.f; a_side = true;
    } else {
        const int n = blk - 2048;
        if (n < 1024)      src = Wq + (size_t)n * 1024;
        else if (n < 2048) src = Wk + (size_t)(n - 1024) * 1024;
        else if (n < 3072) src = Wv + (size_t)(n - 2048) * 1024;
        else if (n < 3088) src = Wa + (size_t)(n - 3072) * 1024;
        else if (n < 3104) src = Wb + (size_t)(n - 3088) * 1024;
        dst = Be + (size_t)n * KEXT;
        scale = 64.f; a_side = false;
    }
    float4 x = src ? *(const float4*)(src + t * 4) : make_float4(0.f,0.f,0.f,0.f);
    x.x *= scale; x.y *= scale; x.z *= scale; x.w *= scale;
    f16x4 h, l;
    h[0] = (_Float16)x.x; l[0] = (_Float16)(x.x - (float)h[0]);
    h[1] = (_Float16)x.y; l[1] = (_Float16)(x.y - (float)h[1]);
    h[2] = (_Float16)x.z; l[2] = (_Float16)(x.z - (float)h[2]);
    h[3] = (_Float16)x.w; l[3] = (_Float16)(x.w - (float)h[3]);
    _Float16* base = dst + t * 4;
    *(f16x4*)(base)        = h;
    *(f16x4*)(base + 1024) = a_side ? l : h;
    *(f16x4*)(base + 2048) = a_side ? h : l;
}

// ---------------------------------------------------------------------------
// qkv MFMA GEMM: 128x128 tile, BK=64, 4 waves each 64x64 (16 MFMA per 8
// ds_read_b128 per 32-slice — the 2:1 m97 ratio; the r8 128x64 shape was
// LDS-read-pipe-bound at 8:6). Epilogue: scale 1/1024, +bias -> qkv; cols
// 3072..3103 -> ab with sigmoid/softplus.
// ---------------------------------------------------------------------------
__global__ __launch_bounds__(256) void mfma_gemm_qkv(
    const _Float16* __restrict__ Ae, const _Float16* __restrict__ Be,
    float* __restrict__ qkv, float* __restrict__ ab,
    const float* __restrict__ bq, const float* __restrict__ bk,
    const float* __restrict__ bv)
{
    __shared__ __align__(16) _Float16 As[2][128 * 32];
    __shared__ __align__(16) _Float16 Bs[2][128 * 32];

    const int tid = threadIdx.x;
    const int wave = tid >> 6;
    const int lane = tid & 63;
    const int bm = blockIdx.y * 128;
    const int bn = blockIdx.x * 128;
    const int wr = (wave >> 1) * 64;
    const int wc = (wave & 1) * 64;

    const int srow = lane >> 2;
    const int scol = (lane & 3) * 8;
    const _Float16* gA0 = Ae + (size_t)(bm + wave * 32 + srow) * KEXT + scol;
    const _Float16* gA1 = gA0 + (size_t)16 * KEXT;
    const _Float16* gB0 = Be + (size_t)(bn + wave * 32 + srow) * KEXT + scol;
    const _Float16* gB1 = gB0 + (size_t)16 * KEXT;
    _Float16* lA0_0 = &As[0][(wave * 32) * 32];
    _Float16* lA1_0 = &As[0][(wave * 32 + 16) * 32];
    _Float16* lB0_0 = &Bs[0][(wave * 32) * 32];
    _Float16* lB1_0 = &Bs[0][(wave * 32 + 16) * 32];
    _Float16* lA0_1 = &As[1][(wave * 32) * 32];
    _Float16* lA1_1 = &As[1][(wave * 32 + 16) * 32];
    _Float16* lB0_1 = &Bs[1][(wave * 32) * 32];
    _Float16* lB1_1 = &Bs[1][(wave * 32 + 16) * 32];

    const int fm = lane & 15;
    const int fq = (lane >> 4) * 8;

    f32x4 acc[4][4] = {};

    for (int k0 = 0; k0 < KEXT; k0 += 64) {
        load_lds16(gA0 + k0,      lA0_0);
        load_lds16(gA1 + k0,      lA1_0);
        load_lds16(gB0 + k0,      lB0_0);
        load_lds16(gB1 + k0,      lB1_0);
        load_lds16(gA0 + k0 + 32, lA0_1);
        load_lds16(gA1 + k0 + 32, lA1_1);
        load_lds16(gB0 + k0 + 32, lB0_1);
        load_lds16(gB1 + k0 + 32, lB1_1);
        __syncthreads();

        #pragma unroll
        for (int s = 0; s < 2; ++s) {
            f16x8 a[4], b[4];
            #pragma unroll
            for (int mt = 0; mt < 4; ++mt)
                a[mt] = *(const f16x8*)&As[s][(wr + mt * 16 + fm) * 32 + fq];
            #pragma unroll
            for (int nt = 0; nt < 4; ++nt)
                b[nt] = *(const f16x8*)&Bs[s][(wc + nt * 16 + fm) * 32 + fq];
            #pragma unroll
            for (int mt = 0; mt < 4; ++mt)
                #pragma unroll
                for (int nt = 0; nt < 4; ++nt)
                    acc[mt][nt] = __builtin_amdgcn_mfma_f32_16x16x32_f16(
                        a[mt], b[nt], acc[mt][nt], 0, 0, 0);
        }
        __syncthreads();
    }

    const int rquad = (lane >> 4) * 4;
    #pragma unroll
    for (int mt = 0; mt < 4; ++mt) {
        #pragma unroll
        for (int nt = 0; nt < 4; ++nt) {
            const int col = bn + wc + nt * 16 + fm;
            #pragma unroll
            for (int i = 0; i < 4; ++i) {
                const int row = bm + wr + mt * 16 + rquad + i;
                float val = acc[mt][nt][i] * (1.0f / 1024.0f);
                if (col < 1024)
                    qkv[(size_t)row * 3072 + col] = val + bq[col];
                else if (col < 2048)
                    qkv[(size_t)row * 3072 + col] = val + bk[col - 1024];
                else if (col < 3072)
                    qkv[(size_t)row * 3072 + col] = val + bv[col - 2048];
                else {
                    const int c = col - 3072;
                    if (c < 16)
                        ab[(size_t)row * 32 + c] = 1.f / (1.f + expf(-val));
                    else if (c < 32)
                        ab[(size_t)row * 32 + c] =
                            fmaxf(val, 0.f) + log1pf(expf(-fabsf(val)));
                }
            }
        }
    }
}

// ---------------------------------------------------------------------------
// Out-projection MFMA GEMM: plain f16 (K=1024), 128x64 tile, BK=64.
// out = (x2hi @ Wo_hi^T) * 64 + bo   (x2 scaled 2^-12, Wo scaled 64)
// ---------------------------------------------------------------------------
__global__ __launch_bounds__(256) void mfma_gemm_out(
    const _Float16* __restrict__ Ae2, const _Float16* __restrict__ Be2,
    float* __restrict__ outp, const float* __restrict__ bo)
{
    __shared__ __align__(16) _Float16 As[2][128 * 32];
    __shared__ __align__(16) _Float16 Bs[2][64 * 32];

    const int tid = threadIdx.x;
    const int wave = tid >> 6;
    const int lane = tid & 63;
    const int bm = blockIdx.y * 128;
    const int bn = blockIdx.x * 64;
    const int wr = (wave >> 1) * 64;
    const int wc = (wave & 1) * 32;

    const int srow = lane >> 2;
    const int scol = (lane & 3) * 8;
    const _Float16* gA0 = Ae2 + (size_t)(bm + wave * 32 + srow) * 1024 + scol;
    const _Float16* gA1 = gA0 + (size_t)16 * 1024;
    const _Float16* gB0 = Be2 + (size_t)(bn + wave * 16 + srow) * 1024 + scol;
    _Float16* lA0_0 = &As[0][(wave * 32) * 32];
    _Float16* lA1_0 = &As[0][(wave * 32 + 16) * 32];
    _Float16* lB0_0 = &Bs[0][(wave * 16) * 32];
    _Float16* lA0_1 = &As[1][(wave * 32) * 32];
    _Float16* lA1_1 = &As[1][(wave * 32 + 16) * 32];
    _Float16* lB0_1 = &Bs[1][(wave * 16) * 32];

    const int fm = lane & 15;
    const int fq = (lane >> 4) * 8;

    f32x4 acc[4][2] = {};

    for (int k0 = 0; k0 < 1024; k0 += 64) {
        load_lds16(gA0 + k0,      lA0_0);
        load_lds16(gA1 + k0,      lA1_0);
        load_lds16(gB0 + k0,      lB0_0);
        load_lds16(gA0 + k0 + 32, lA0_1);
        load_lds16(gA1 + k0 + 32, lA1_1);
        load_lds16(gB0 + k0 + 32, lB0_1);
        __syncthreads();

        #pragma unroll
        for (int s = 0; s < 2; ++s) {
            f16x8 a[4], b[2];
            #pragma unroll
            for (int mt = 0; mt < 4; ++mt)
                a[mt] = *(const f16x8*)&As[s][(wr + mt * 16 + fm) * 32 + fq];
            #pragma unroll
            for (int nt = 0; nt < 2; ++nt)
                b[nt] = *(const f16x8*)&Bs[s][(wc + nt * 16 + fm) * 32 + fq];
            #pragma unroll
            for (int mt = 0; mt < 4; ++mt)
                #pragma unroll
                for (int nt = 0; nt < 2; ++nt)
                    acc[mt][nt] = __builtin_amdgcn_mfma_f32_16x16x32_f16(
                        a[mt], b[nt], acc[mt][nt], 0, 0, 0);
        }
        __syncthreads();
    }

    const int rquad = (lane >> 4) * 4;
    #pragma unroll
    for (int mt = 0; mt < 4; ++mt) {
        #pragma unroll
        for (int nt = 0; nt < 2; ++nt) {
            const int col = bn + wc + nt * 16 + fm;
            #pragma unroll
            for (int i = 0; i < 4; ++i) {
                const int row = bm + wr + mt * 16 + rquad + i;
                outp[(size_t)row * 1024 + col] = acc[mt][nt][i] * 64.f + bo[col];
            }
        }
    }
}

// ---------------------------------------------------------------------------
// DPP 16-lane reduction (xor1, xor2, row_ror:4, row_ror:8 -> all lanes hold sum)
// ---------------------------------------------------------------------------
template <int CTRL>
__device__ __forceinline__ float dpp_addf(float x) {
    int y = __builtin_amdgcn_update_dpp(0, __builtin_bit_cast(int, x),
                                        CTRL, 0xF, 0xF, true);
    return x + __builtin_bit_cast(float, y);
}
__device__ __forceinline__ float red16(float x) {
    x = dpp_addf<0xB1>(x);
    x = dpp_addf<0x4E>(x);
    x = dpp_addf<0x124>(x);
    x = dpp_addf<0x128>(x);
    return x;
}

// ---------------------------------------------------------------------------
// Gated delta recurrence (r8 verbatim: 121.4 us known-good). 512 blocks x 64
// threads; blk%32 = chain (XCD co-location), blk/32 = 4-row slice.
// ---------------------------------------------------------------------------
__global__ __launch_bounds__(64) void gdn_recurrence(
    const float* __restrict__ qkv, const float* __restrict__ ab,
    float* __restrict__ att)
{
    __shared__ __align__(16) float ks[2][RCT][64];
    __shared__ __align__(16) float qs[2][RCT][64];
    __shared__ __align__(16) float vs_[2][RCT][4];
    __shared__ __align__(16) float gab[2][RCT][2];

    const int blk = blockIdx.x;
    const int bh = blk & 31;          // chain (XCD co-location)
    const int s  = blk >> 5;          // row-slice 0..15
    const int b  = bh >> 4;
    const int h  = bh & 15;
    const int lane = threadIdx.x;
    const int rl = lane >> 4;         // local row 0..3
    const int el = lane & 15;         // e-slice
    const int e0 = el * 4;
    const int r0 = s * 4;

    const float* qb  = qkv + (size_t)b * LL * 3072 + h * 64;
    const float* kb  = qb + 1024;
    const float* vb  = qb + 2048 + r0;
    const float* abp = ab + (size_t)b * LL * 32 + h;
    float* op = att + ((size_t)(b * NH + h) * DD + r0 + rl) * LL;

    const int st = lane >> 4;          // t-within-4 for staging
    const int sd = (lane & 15) * 4;    // d offset

    float S0 = 0.f, S1 = 0.f, S2 = 0.f, S3 = 0.f;

    // ---- async-stage k/q chunk 0, reg-load v/ab chunk 0 ----
    {
        const size_t ro = (size_t)st * 3072 + sd;
        #pragma unroll
        for (int m = 0; m < 8; ++m) {
            load_lds16(kb + ro + (size_t)m * 4 * 3072, &ks[0][m * 4][0]);
            load_lds16(qb + ro + (size_t)m * 4 * 3072, &qs[0][m * 4][0]);
        }
        float4 pv = make_float4(0.f,0.f,0.f,0.f);
        if (lane < RCT) pv = *(const float4*)(vb + (size_t)lane * 3072);
        float pab = (lane < 32) ? abp[(size_t)lane * 32]
                                : abp[(size_t)(lane - 32) * 32 + 16];
        if (lane < RCT) *(float4*)&vs_[0][lane][0] = pv;
        if (lane < 32) gab[0][lane][0] = pab;
        else           gab[0][lane - 32][1] = pab;
    }
    __syncthreads();

    const int NCHUNK = LL / RCT;
    for (int c = 0; c < NCHUNK; ++c) {
        const int cur = c & 1, nxt = cur ^ 1;
        const bool more = (c + 1 < NCHUNK);

        // issue async staging for chunk c+1; tiny reg prefetch for v/ab
        float4 pv = make_float4(0.f,0.f,0.f,0.f);
        float pab = 0.f;
        if (more) {
            const size_t t0 = (size_t)(c + 1) * RCT;
            const size_t ro = (t0 + st) * 3072 + sd;
            #pragma unroll
            for (int m = 0; m < 8; ++m) {
                load_lds16(kb + ro + (size_t)m * 4 * 3072, &ks[nxt][m * 4][0]);
                load_lds16(qb + ro + (size_t)m * 4 * 3072, &qs[nxt][m * 4][0]);
            }
            if (lane < RCT) pv = *(const float4*)(vb + (t0 + lane) * 3072);
            pab = (lane < 32) ? abp[(t0 + lane) * 32]
                              : abp[(t0 + lane - 32) * 32 + 16];
        }

        // ---- 32 steps from buffer cur, 1-step LDS->reg prefetch ----
        float4 kc = *(const float4*)&ks[cur][0][e0];
        float4 qc = *(const float4*)&qs[cur][0][e0];
        float vc = vs_[cur][0][rl];
        float2 abc = *(const float2*)&gab[cur][0][0];
        float ac = abc.x;
        float bc = abc.y;

        float o0 = 0.f, o1 = 0.f, o2 = 0.f;
        #pragma unroll 4
        for (int t = 0; t < RCT; ++t) {
            const int tn = (t + 1) & (RCT - 1);
            float4 kn = *(const float4*)&ks[cur][tn][e0];
            float4 qn = *(const float4*)&qs[cur][tn][e0];
            const float vn = vs_[cur][tn][rl];
            const float2 abn = *(const float2*)&gab[cur][tn][0];

            // sk = (S . k) row-dot
            float p0 = fmaf(S1, kc.y, S0 * kc.x);
            float p1 = fmaf(S3, kc.w, S2 * kc.z);
            float sk = red16(p0 + p1);

            const float cf = bc * fmaf(-ac, sk, vc);

            S0 = fmaf(ac, S0, cf * kc.x);
            S1 = fmaf(ac, S1, cf * kc.y);
            S2 = fmaf(ac, S2, cf * kc.z);
            S3 = fmaf(ac, S3, cf * kc.w);

            float q0 = fmaf(S1, qc.y, S0 * qc.x);
            float q1 = fmaf(S3, qc.w, S2 * qc.z);
            float o = red16(q0 + q1);

            const int ph = t & 3;
            if (ph == 0) o0 = o;
            else if (ph == 1) o1 = o;
            else if (ph == 2) o2 = o;
            else if (el == 0)
                *(float4*)(op + c * RCT + t - 3) = make_float4(o0, o1, o2, o);

            kc = kn; qc = qn; vc = vn; ac = abn.x; bc = abn.y;
        }

        // commit v/ab prefetch into next buffer, then publish
        if (more) {
            if (lane < RCT) *(float4*)&vs_[nxt][lane][0] = pv;
            if (lane < 32) gab[nxt][lane][0] = pab;
            else           gab[nxt][lane - 32][1] = pab;
        }
        __syncthreads();
    }
}

// ---------------------------------------------------------------------------
// Fused: residual depthwise causal conv (bug-compat reshaped view) +
// transpose back + f16 convert (hi only) for the out-projection A matrix.
// ---------------------------------------------------------------------------
__global__ __launch_bounds__(256) void conv_convert(
    const float* __restrict__ att, const float* __restrict__ Wconv,
    _Float16* __restrict__ Ae2)
{
    __shared__ float yt[112][68];
    const int lb = blockIdx.x;
    const int h  = blockIdx.y;
    const int b  = blockIdx.z;
    const int tid = threadIdx.x;

    {
        const int d = tid >> 2;
        const int part = tid & 3;
        const float* src  = att + ((size_t)(b * NH + h) * DD + d) * LL;
        const float* srcm = src - (size_t)DD * LL;
        #pragma unroll
        for (int m = 0; m < 7; ++m) {
            const int off = (part * 7 + m) * 4;
            const int lg = lb * 64 - 48 + off;
            float4 v;
            if (lg >= 0)      v = *(const float4*)(src + lg);
            else if (h > 0)   v = *(const float4*)(srcm + lg + 1024);
            else              v = make_float4(0.f, 0.f, 0.f, 0.f);
            yt[off + 0][d] = v.x; yt[off + 1][d] = v.y;
            yt[off + 2][d] = v.z; yt[off + 3][d] = v.w;
        }
    }
    __syncthreads();

    float4 w[4];
    #pragma unroll
    for (int k = 0; k < 4; ++k)
        w[k] = ((const float4*)Wconv)[tid * 4 + k];

    const int d0 = (tid & 15) * 4;
    const int lq = tid >> 4;
    const float sc = 1.f / 4096.f;

    #pragma unroll
    for (int rr = 0; rr < 4; ++rr) {
        const int ll = rr * 16 + lq;
        float y0[4], y1[4], y2[4], y3[4];
        *(float4*)y0 = *(const float4*)&yt[ll +  0][d0];
        *(float4*)y1 = *(const float4*)&yt[ll + 16][d0];
        *(float4*)y2 = *(const float4*)&yt[ll + 32][d0];
        *(float4*)y3 = *(const float4*)&yt[ll + 48][d0];
        f16x4 hi;
        #pragma unroll
        for (int k = 0; k < 4; ++k) {
            float acc = y3[k];
            acc = fmaf(w[k].x, y0[k], acc);
            acc = fmaf(w[k].y, y1[k], acc);
            acc = fmaf(w[k].z, y2[k], acc);
            acc = fmaf(w[k].w, y3[k], acc);
            hi[k] = (_Float16)(acc * sc);
        }
        const size_t row = (size_t)b * 1024 + h * 64 + lb * 4 + rr;
        *(f16x4*)(Ae2 + row * 1024 + tid * 4) = hi;
    }
}

// ---------------------------------------------------------------------------
extern "C" void kernel_launch(void* const* d_in, const int* in_sizes, int n_in,
                              void* d_out, int out_size, void* d_ws, size_t ws_size,
                              hipStream_t stream)
{
    const float* hs    = (const float*)d_in[0];
    const float* Wq    = (const float*)d_in[1];
    const float* bq    = (const float*)d_in[2];
    const float* Wk    = (const float*)d_in[3];
    const float* bk    = (const float*)d_in[4];
    const float* Wv    = (const float*)d_in[5];
    const float* bv    = (const float*)d_in[6];
    const float* Wa    = (const float*)d_in[7];
    const float* Wb    = (const float*)d_in[8];
    const float* Wconv = (const float*)d_in[9];
    const float* Wo    = (const float*)d_in[10];
    const float* bo    = (const float*)d_in[11];
    float* out = (float*)d_out;

    // workspace layout
    char* w = (char*)d_ws;
    float* qkv = (float*)w;        w += (size_t)MM * 3072 * 4;      // 25.2 MB
    float* att = (float*)w;        w += (size_t)MM * 1024 * 4;      //  8.4 MB ([B][NH][D][L])
    float* ab  = (float*)w;        w += (size_t)MM * 32 * 4;        //  0.26 MB
    _Float16* Ae  = (_Float16*)w;  w += (size_t)MM * KEXT * 2;      // 12.6 MB
    _Float16* Be  = (_Float16*)w;  w += (size_t)NB_QKV * KEXT * 2;  // 19.7 MB
    _Float16* Ae2 = (_Float16*)w;  w += (size_t)MM * 1024 * 2;      //  4.2 MB
    _Float16* Be2 = (_Float16*)w;  w += (size_t)1024 * 1024 * 2;    //  2.1 MB

    // 1) merged split-f16 conversions (hs->Ae, W*->Be, Wo->Be2)
    hipLaunchKernelGGL(convert_front, dim3(2048 + NB_QKV + 1024), dim3(256), 0, stream,
                       hs, Wq, Wk, Wv, Wa, Wb, Wo, Ae, Be, Be2);

    // 2) fused q/k/v/alpha/beta projection (128x128, BK=64, 64x64 wave tiles)
    hipLaunchKernelGGL(mfma_gemm_qkv, dim3(NB_QKV / 128, MM / 128), dim3(256), 0, stream,
                       Ae, Be, qkv, ab, bq, bk, bv);

    // 3) gated delta recurrence (r8 verbatim, 512 one-wave blocks)
    hipLaunchKernelGGL(gdn_recurrence, dim3(512), dim3(64), 0, stream, qkv, ab, att);

    // 4) fused conv + transpose + f16 convert (hi only, writes Ae2)
    hipLaunchKernelGGL(conv_convert, dim3(16, 16, BB), dim3(256), 0, stream,
                       att, Wconv, Ae2);

    // 5) out-projection (plain f16, K=1024, 128x64 tiles -> 256 blocks)
    hipLaunchKernelGGL(mfma_gemm_out, dim3(1024 / 64, MM / 128), dim3(256), 0, stream,
                       Ae2, Be2, out, bo);
}